// Round 12
// baseline (3448.384 us; speedup 1.0000x reference)
//
#include <hip/hip_runtime.h>

// TerminalGRU: B=256 T=256 D=512 H=1024 C=128
// Round-12: fold the gates GEMM INTO the scan's wait bubble. Round-9 showed
// co-resident helper BLOCKS interfere; here the SAME scan blocks run 3 gates
// kk-units (48 MFMA, ~0.5us) per step after the notify store, covering all
// 1536 tiles of gates(c+1) in 32 steps (6 tiles/block, persistent gacc).
// A-operands f32-direct (bit-identical f2b->MFMA); Xb deleted; gx double-
// buffered (ws ~146MB < proven 162MB). Logits stays a small dispatch.
// Pipeline: prep -> gatesF(0) -> loop{ scan+bubble(c); logits(c) }

#define DEVI __device__ __forceinline__

typedef __bf16 bf16x8 __attribute__((ext_vector_type(8)));
typedef float f32x4 __attribute__((ext_vector_type(4)));
typedef unsigned long long u64;

static constexpr int Bb = 256, Tt = 256, Dd = 512, Hh = 1024, Cc = 128;
static constexpr int G3 = 3072, DC = 640, TC = 32, NC = Tt / TC;
static constexpr int SLOTS = TC + 1;  // 33-slot h ring

DEVI unsigned short f2b(float f) {
  union { float f; unsigned u; } v; v.f = f;
  unsigned r = v.u + 0x7FFFu + ((v.u >> 16) & 1u);
  return (unsigned short)(r >> 16);
}
DEVI float b2f(unsigned short h) {
  union { unsigned u; float f; } v; v.u = ((unsigned)h) << 16; return v.f;
}

union HB { unsigned short s[8]; bf16x8 v; };

// ---------------- prep kernels ----------------

__global__ __launch_bounds__(256) void k_cvt(const float* __restrict__ x,
                                             unsigned short* __restrict__ o, int n) {
  int i = (blockIdx.x * 256 + threadIdx.x) * 8;
  if (i >= n) return;
  float4 a = *(const float4*)(x + i), b = *(const float4*)(x + i + 4);
  uint4 u;
  u.x = (unsigned)f2b(a.x) | ((unsigned)f2b(a.y) << 16);
  u.y = (unsigned)f2b(a.z) | ((unsigned)f2b(a.w) << 16);
  u.z = (unsigned)f2b(b.x) | ((unsigned)f2b(b.y) << 16);
  u.w = (unsigned)f2b(b.z) | ((unsigned)f2b(b.w) << 16);
  *(uint4*)(o + i) = u;
}

__global__ __launch_bounds__(256) void k_cvt_wa(const float* __restrict__ Wih,
                                                unsigned short* __restrict__ Wa) {
  int u = blockIdx.x * 256 + threadIdx.x;
  int g = u >> 6, d = (u & 63) * 8;
  const float* p = Wih + (size_t)g * DC + d;
  float4 a = *(const float4*)p, b = *(const float4*)(p + 4);
  uint4 o;
  o.x = (unsigned)f2b(a.x) | ((unsigned)f2b(a.y) << 16);
  o.y = (unsigned)f2b(a.z) | ((unsigned)f2b(a.w) << 16);
  o.z = (unsigned)f2b(b.x) | ((unsigned)f2b(b.y) << 16);
  o.w = (unsigned)f2b(b.z) | ((unsigned)f2b(b.w) << 16);
  *(uint4*)(Wa + (size_t)g * Dd + d) = o;
}

__global__ __launch_bounds__(256) void k_cvt_wct(const float* __restrict__ Wih,
                                                 unsigned short* __restrict__ WcT) {
  int g = blockIdx.x * 256 + threadIdx.x;
  int c = blockIdx.y;
  WcT[(size_t)c * G3 + g] = f2b(Wih[(size_t)g * DC + Dd + c]);
}

__global__ __launch_bounds__(256) void k_pid(const float* __restrict__ ts,
                                             int* __restrict__ pid) {
  int bt = blockIdx.x * 256 + threadIdx.x;
  int t = bt & (Tt - 1);
  if (t == 0) { pid[bt] = -1; return; }
  const float* p = ts + (size_t)(bt - 1) * Cc;
  int id = 0;
  for (int c = 0; c < Cc; c += 4) {
    float4 v = *(const float4*)(p + c);
    if (v.x > 0.5f) id = c;
    if (v.y > 0.5f) id = c + 1;
    if (v.z > 0.5f) id = c + 2;
    if (v.w > 0.5f) id = c + 3;
  }
  pid[bt] = id;
}

// ---------------- gates helpers (f32-direct A) ----------------
DEVI bf16x8 ld_a_f32(const float* __restrict__ X, int m, int t0c, int k) {
  int b = m >> 5, tl = m & 31;
  const float* p = X + ((size_t)(b * Tt + t0c + tl)) * Dd + k;
  float4 x = *(const float4*)p, y = *(const float4*)(p + 4);
  HB r;
  r.s[0] = f2b(x.x); r.s[1] = f2b(x.y); r.s[2] = f2b(x.z); r.s[3] = f2b(x.w);
  r.s[4] = f2b(y.x); r.s[5] = f2b(y.y); r.s[6] = f2b(y.z); r.s[7] = f2b(y.w);
  return r.v;
}

// full-tile f32-direct gates (prologue only)
DEVI void gates_tile_f32(int mi, int ni, const float* __restrict__ X,
                         const unsigned short* __restrict__ Wa,
                         const unsigned short* __restrict__ WcT,
                         const float* __restrict__ bih,
                         const int* __restrict__ pid,
                         unsigned short* __restrict__ gx, int t0c) {
  int m0 = mi * 128, n0 = ni * 128;
  int l = threadIdx.x & 63, w = threadIdx.x >> 6;
  int wm = w >> 1, wn = w & 1;
  int r0 = m0 + 64 * wm, c0 = n0 + 64 * wn;
  int lr = l & 15, lk = (l >> 4) * 8;
  f32x4 acc[4][4] = {};
  for (int kk = 0; kk < 16; ++kk) {
    int k = kk * 32 + lk;
    bf16x8 a[4], b[4];
#pragma unroll
    for (int mf = 0; mf < 4; ++mf)
      a[mf] = ld_a_f32(X, r0 + 16 * mf + lr, t0c, k);
#pragma unroll
    for (int nf = 0; nf < 4; ++nf)
      b[nf] = *(const bf16x8*)(Wa + (size_t)(c0 + 16 * nf + lr) * Dd + k);
#pragma unroll
    for (int mf = 0; mf < 4; ++mf)
#pragma unroll
      for (int nf = 0; nf < 4; ++nf)
        acc[mf][nf] = __builtin_amdgcn_mfma_f32_16x16x32_bf16(a[mf], b[nf], acc[mf][nf], 0, 0, 0);
  }
  int ri = (l >> 4) * 4;
  for (int mf = 0; mf < 4; ++mf) {
    int rowb = r0 + 16 * mf + ri;
    int pd[4];
#pragma unroll
    for (int i = 0; i < 4; ++i) {
      int rr = rowb + i;
      pd[i] = pid[(size_t)(rr >> 5) * Tt + t0c + (rr & 31)];
    }
    for (int nf = 0; nf < 4; ++nf) {
      int g = c0 + 16 * nf + lr;
      float bi = bih[g];
#pragma unroll
      for (int i = 0; i < 4; ++i) {
        float v = acc[mf][nf][i] + bi;
        if (pd[i] >= 0) v += b2f(WcT[(size_t)pd[i] * G3 + g]);
        gx[(size_t)(rowb + i) * G3 + g] = f2b(v);
      }
    }
  }
}

__global__ __launch_bounds__(256) void k_gatesF(const float* __restrict__ X,
                                                const unsigned short* __restrict__ Wa,
                                                const unsigned short* __restrict__ WcT,
                                                const float* __restrict__ bih,
                                                const int* __restrict__ pid,
                                                unsigned short* __restrict__ gx, int t0c) {
  gates_tile_f32(blockIdx.x, blockIdx.y, X, Wa, WcT, bih, pid, gx, t0c);
}

// ---------------- logits ----------------
__global__ __launch_bounds__(256) void k_logits(const unsigned short* __restrict__ hsc,
                                                const unsigned short* __restrict__ Wo,
                                                const float* __restrict__ bout,
                                                float* __restrict__ out, int t0) {
  int blk = blockIdx.x;
  int l = threadIdx.x & 63, w = threadIdx.x >> 6;
  int lr = l & 15, lk = (l >> 4) * 8;
  int r0 = blk * 64 + 16 * w;
  f32x4 acc[8] = {};
  for (int kk = 0; kk < 32; ++kk) {
    int k = kk * 32 + lk;
    bf16x8 a = *(const bf16x8*)(hsc + (size_t)(r0 + lr) * Hh + k);
#pragma unroll
    for (int nf = 0; nf < 8; ++nf) {
      bf16x8 b = *(const bf16x8*)(Wo + (size_t)(16 * nf + lr) * Hh + k);
      acc[nf] = __builtin_amdgcn_mfma_f32_16x16x32_bf16(a, b, acc[nf], 0, 0, 0);
    }
  }
  int ri = (l >> 4) * 4;
  for (int nf = 0; nf < 8; ++nf) {
    int c = 16 * nf + lr;
    float bo = bout[c];
#pragma unroll
    for (int i = 0; i < 4; ++i) {
      int m = r0 + ri + i;
      int grow = (m >> 5) * Tt + t0 + (m & 31);
      out[(size_t)grow * Cc + c] = acc[nf][i] + bo;
    }
  }
}

// ---------------- recurrent scan + gates bubble ----------------
// 256 blocks x 256 threads. mg = bid&7 (group/XCD, rows [32mg,+32)),
// cb = bid>>3 (hcols [32cb,+32)). Wave w: K-slice [256w,+256).
// notify[mg][32] epoch words; ALL waves poll. After each step's notify store,
// 3 gates kk-units for chunk c+1 run in the wait bubble (6 tiles/block total).
__global__ __launch_bounds__(256, 1) void k_scan(
    const unsigned short* __restrict__ Whh, const float* __restrict__ bhh,
    const unsigned short* __restrict__ gx, unsigned short* __restrict__ hring,
    unsigned short* __restrict__ hsc, unsigned int* __restrict__ notify, int t0,
    const float* __restrict__ gruX, const unsigned short* __restrict__ Wa,
    const unsigned short* __restrict__ WcT, const float* __restrict__ bih,
    const int* __restrict__ pid, unsigned short* __restrict__ gxN, int doGates) {
  __shared__ float red[4 * 32 * 100];  // [wave][row32][3*32 pad100] = 51.2KB
  const int tid = threadIdx.x;
  const int l = tid & 63, w = tid >> 6;
  const int bid = blockIdx.x;
  const int mg = bid & 7, cb = bid >> 3;
  const int lr = l & 15, lk = (l >> 4) * 8;
  const int hcolBase = 32 * cb;
  const int ri = (l >> 4) * 4;
  const int wm = w >> 1, wn = w & 1;
  const int t0n = t0 + TC;  // bubble gates target chunk

  // resident W_hh fragments: 3 gates x 2 col-halves x 8 k-steps
  bf16x8 Breg[6][8];
#pragma unroll
  for (int nf = 0; nf < 6; ++nf) {
    int wrow = (nf >> 1) * Hh + hcolBase + (nf & 1) * 16 + lr;
#pragma unroll
    for (int kk = 0; kk < 8; ++kk) {
      int k = 256 * w + 32 * kk + lk;
      Breg[nf][kk] = *(const bf16x8*)(Whh + (size_t)wrow * Hh + k);
    }
  }

  // epilogue mapping: thread -> 1 row x 4 cols (8-byte h I/O)
  const int erow = tid >> 3, ej0 = (tid & 7) * 4;
  const int eb = 32 * mg + erow;
  const int ecol = hcolBase + ej0;
  const float4 bhr4 = *(const float4*)(bhh + ecol);
  const float4 bhz4 = *(const float4*)(bhh + Hh + ecol);
  const float4 bhn4 = *(const float4*)(bhh + 2 * Hh + ecol);

  u64 hsave = 0;          // own h slice carried in registers across steps
  f32x4 gacc[4][4] = {};  // bubble gates accumulator (one tile in flight)

  for (int tl = 0; tl < TC; ++tl) {
    const int t = t0 + tl;
    const unsigned short* hcur = hring + (size_t)(t % SLOTS) * (Bb * Hh);
    u64* hnq = (u64*)hring + (size_t)((t + 1) % SLOTS) * (Bb * Hh / 4);

    // prefetch gx for this step (independent of the wait)
    const size_t gxo = (size_t)(eb * TC + tl) * G3;
    uint2 gr = *(const uint2*)(gx + gxo + ecol);
    uint2 gz = *(const uint2*)(gx + gxo + Hh + ecol);
    uint2 gn = *(const uint2*)(gx + gxo + 2 * Hh + ecol);

    // wait: all 32 blocks of this group produced h[t]; every wave polls
    if (t > 0) {
      const unsigned int* np = notify + (mg << 6) + (l & 31);
      for (;;) {
        unsigned int v = __hip_atomic_load(np, __ATOMIC_RELAXED,
                                           __HIP_MEMORY_SCOPE_AGENT);
        if (__all((int)(v >= (unsigned)t))) break;
      }
    }
    asm volatile("" ::: "memory");

    u64 hprev = (tl == 0) ? *(const u64*)(hcur + (size_t)eb * Hh + ecol) : hsave;

    f32x4 acc[2][6] = {};
#pragma unroll
    for (int kk = 0; kk < 8; ++kk) {
      int k = 256 * w + 32 * kk + lk;
      bf16x8 a[2];
#pragma unroll
      for (int mf = 0; mf < 2; ++mf)
        a[mf] = *(const bf16x8*)(hcur + (size_t)(32 * mg + 16 * mf + lr) * Hh + k);
#pragma unroll
      for (int mf = 0; mf < 2; ++mf)
#pragma unroll
        for (int nf = 0; nf < 6; ++nf)
          acc[mf][nf] = __builtin_amdgcn_mfma_f32_16x16x32_bf16(a[mf], Breg[nf][kk], acc[mf][nf], 0, 0, 0);
    }

    // partials -> LDS (col = gate*32 + half*16 + lr)
#pragma unroll
    for (int mf = 0; mf < 2; ++mf)
#pragma unroll
      for (int nf = 0; nf < 6; ++nf)
#pragma unroll
        for (int i = 0; i < 4; ++i)
          red[(w * 32 + 16 * mf + ri + i) * 100 + (nf >> 1) * 32 + (nf & 1) * 16 + lr] = acc[mf][nf][i];
    __syncthreads();

    // reduce 4 wave-partials + gate math, 1 row x 4 cols per thread
    f32x4 vr = {}, vz = {}, vn = {};
#pragma unroll
    for (int w2 = 0; w2 < 4; ++w2) {
      const float* rp = &red[(w2 * 32 + erow) * 100];
      vr += *(const f32x4*)(rp + ej0);
      vz += *(const f32x4*)(rp + 32 + ej0);
      vn += *(const f32x4*)(rp + 64 + ej0);
    }
    unsigned short grs[4] = {(unsigned short)gr.x, (unsigned short)(gr.x >> 16),
                             (unsigned short)gr.y, (unsigned short)(gr.y >> 16)};
    unsigned short gzs[4] = {(unsigned short)gz.x, (unsigned short)(gz.x >> 16),
                             (unsigned short)gz.y, (unsigned short)(gz.y >> 16)};
    unsigned short gns[4] = {(unsigned short)gn.x, (unsigned short)(gn.x >> 16),
                             (unsigned short)gn.y, (unsigned short)(gn.y >> 16)};
    u64 ho = 0;
#pragma unroll
    for (int i = 0; i < 4; ++i) {
      float hr = vr[i] + (&bhr4.x)[i];
      float hz = vz[i] + (&bhz4.x)[i];
      float hn = vn[i] + (&bhn4.x)[i];
      float xr = b2f(grs[i]), xz = b2f(gzs[i]), xn = b2f(gns[i]);
      float rg = 1.f / (1.f + __expf(-(xr + hr)));
      float zg = 1.f / (1.f + __expf(-(xz + hz)));
      float pre = xn + rg * hn;
      pre = fminf(fmaxf(pre, -15.f), 15.f);
      float e = __expf(-2.f * pre);
      float ng = (1.f - e) / (1.f + e);
      float hp = b2f((unsigned short)(hprev >> (16 * i)));
      float hv = (1.f - zg) * ng + zg * hp;
      ho |= (u64)f2b(hv) << (16 * i);
    }
    __hip_atomic_store(hnq + ((size_t)eb * Hh + ecol) / 4, ho,
                       __ATOMIC_RELAXED, __HIP_MEMORY_SCOPE_AGENT);
    hsave = ho;

    asm volatile("s_waitcnt vmcnt(0)" ::: "memory");  // h stores acked at MALL
    __syncthreads();  // all waves drained; also protects red[] reuse
    if (tid == 0)
      __hip_atomic_store(notify + (mg << 6) + cb, (unsigned)(t + 1),
                         __ATOMIC_RELAXED, __HIP_MEMORY_SCOPE_AGENT);
    // history write AFTER notify -- off the critical path
    *(u64*)(hsc + (size_t)(eb * TC + tl) * Hh + ecol) = ho;

    // ---- gates bubble: 3 kk-units of gates(c+1) in the wait window ----
    if (doGates) {
      for (int j = 0; j < 3; ++j) {
        int u = tl * 3 + j;            // 0..95
        int tau = bid * 6 + (u >> 4);  // this block's 6 tiles of 1536
        int kk = u & 15;
        int mi = tau & 63, ni = tau >> 6;
        int r0g = mi * 128 + 64 * wm, c0g = ni * 128 + 64 * wn;
        int kg = kk * 32 + lk;
        bf16x8 a[4], b[4];
#pragma unroll
        for (int mf = 0; mf < 4; ++mf)
          a[mf] = ld_a_f32(gruX, r0g + 16 * mf + lr, t0n, kg);
#pragma unroll
        for (int nf = 0; nf < 4; ++nf)
          b[nf] = *(const bf16x8*)(Wa + (size_t)(c0g + 16 * nf + lr) * Dd + kg);
#pragma unroll
        for (int mf = 0; mf < 4; ++mf)
#pragma unroll
          for (int nf = 0; nf < 4; ++nf)
            gacc[mf][nf] = __builtin_amdgcn_mfma_f32_16x16x32_bf16(a[mf], b[nf], gacc[mf][nf], 0, 0, 0);
        if (kk == 15) {  // tile complete: epilogue + reset acc
          for (int mf = 0; mf < 4; ++mf) {
            int rowb = r0g + 16 * mf + ri;
            int pd[4];
#pragma unroll
            for (int i = 0; i < 4; ++i) {
              int rr = rowb + i;
              pd[i] = pid[(size_t)(rr >> 5) * Tt + t0n + (rr & 31)];
            }
            for (int nf = 0; nf < 4; ++nf) {
              int g = c0g + 16 * nf + lr;
              float bi = bih[g];
#pragma unroll
              for (int i = 0; i < 4; ++i) {
                float v = gacc[mf][nf][i] + bi;
                if (pd[i] >= 0) v += b2f(WcT[(size_t)pd[i] * G3 + g]);
                gxN[(size_t)(rowb + i) * G3 + g] = f2b(v);
              }
            }
          }
#pragma unroll
          for (int mf = 0; mf < 4; ++mf)
#pragma unroll
            for (int nf = 0; nf < 4; ++nf)
              gacc[mf][nf] = f32x4{};
        }
      }
    }
  }
}

// ---------------- launch ----------------
extern "C" void kernel_launch(void* const* d_in, const int* in_sizes, int n_in,
                              void* d_out, int out_size, void* d_ws, size_t ws_size,
                              hipStream_t stream) {
  const float* gru = (const float*)d_in[0];
  const float* ts  = (const float*)d_in[1];
  const float* Wih = (const float*)d_in[2];
  const float* bih = (const float*)d_in[3];
  const float* Whh = (const float*)d_in[4];
  const float* bhh = (const float*)d_in[5];
  const float* Wou = (const float*)d_in[6];
  const float* bou = (const float*)d_in[7];
  float* out = (float*)d_out;

  char* ws = (char*)d_ws;
  size_t off = 0;
  auto alloc = [&](size_t bytes) -> void* {
    void* p = ws + off;
    off += (bytes + 255) & ~(size_t)255;
    return p;
  };
  unsigned short* Wa    = (unsigned short*)alloc((size_t)G3 * Dd * 2);        // 3.1MB
  unsigned short* WcT   = (unsigned short*)alloc((size_t)Cc * G3 * 2);        // 0.8MB
  unsigned short* Whb   = (unsigned short*)alloc((size_t)G3 * Hh * 2);        // 6.3MB
  unsigned short* Wob   = (unsigned short*)alloc((size_t)Cc * Hh * 2);        // 0.26MB
  int*            pid   = (int*)alloc((size_t)Bb * Tt * 4);                   // 0.26MB
  unsigned short* hring = (unsigned short*)alloc((size_t)SLOTS * Bb * Hh * 2);// 17.3MB
  unsigned int*   nfy   = (unsigned int*)alloc((size_t)8 * 64 * 4);
  unsigned short* gxb0  = (unsigned short*)alloc((size_t)Bb * TC * G3 * 2);   // 50.3MB
  unsigned short* gxb1  = (unsigned short*)alloc((size_t)Bb * TC * G3 * 2);   // 50.3MB
  unsigned short* hsc   = (unsigned short*)alloc((size_t)Bb * TC * Hh * 2);   // 16.8MB
  if (ws_size < off) return;  // ~146MB; round-9 proved >=162MB exists
  unsigned short* gxb[2] = { gxb0, gxb1 };

  k_cvt<<<(G3 * Hh) / 2048, 256, 0, stream>>>(Whh, Whb, G3 * Hh);
  k_cvt<<<(Cc * Hh) / 2048, 256, 0, stream>>>(Wou, Wob, Cc * Hh);
  k_cvt_wa<<<(G3 * 64) / 256, 256, 0, stream>>>(Wih, Wa);
  k_cvt_wct<<<dim3(G3 / 256, Cc), 256, 0, stream>>>(Wih, WcT);
  k_pid<<<(Bb * Tt) / 256, 256, 0, stream>>>(ts, pid);
  hipMemsetAsync(hring, 0, (size_t)Bb * Hh * 2, stream);  // slot 0 = h(0) = 0
  hipMemsetAsync(nfy, 0, (size_t)8 * 64 * 4, stream);

  // prologue: gates for chunk 0 (one-time f32-direct)
  k_gatesF<<<dim3(64, 24), 256, 0, stream>>>(gru, Wa, WcT, bih, pid, gxb[0], 0);

  for (int c = 0; c < NC; ++c) {
    int t0 = c * TC;
    k_scan<<<dim3(256), dim3(256), 0, stream>>>(
        Whb, bhh, gxb[c & 1], hring, hsc, nfy, t0,
        gru, Wa, WcT, bih, pid, gxb[(c + 1) & 1], (c + 1 < NC) ? 1 : 0);
    k_logits<<<(Bb * TC) / 64, 256, 0, stream>>>(hsc, Wob, bou, out, t0);
  }
}

// Round 13
// 2352.785 us; speedup vs baseline: 1.4657x; 1.4657x over previous
//
#include <hip/hip_runtime.h>

// TerminalGRU: B=256 T=256 D=512 H=1024 C=128
// Round-13: revert R12 bubble (scan must own its loop: R9 = block-level
// interference, R12 = in-line work both regress). Round-11 pipeline restored
// (scan 175us proven); the lever is the combo's gates GEMM: direct global
// loads (~200 TF, A re-read 24x / B 64x) -> reg-staged LDS 128x128 tile,
// BK=64, padded stride 72 (144B rows = 2-way bank alias, free), ds_read_b128
// fragments. Same K-accumulation order => bit-identical. Logits unchanged.
// Pipeline: prep+cvtX -> gates(0) -> loop{ scan(c); combo: gates(c+1)+logits(c) }

#define DEVI __device__ __forceinline__

typedef __bf16 bf16x8 __attribute__((ext_vector_type(8)));
typedef float f32x4 __attribute__((ext_vector_type(4)));
typedef unsigned long long u64;

static constexpr int Bb = 256, Tt = 256, Dd = 512, Hh = 1024, Cc = 128;
static constexpr int G3 = 3072, DC = 640, TC = 32, NC = Tt / TC;
static constexpr int SLOTS = TC + 1;  // 33-slot h ring
static constexpr int LDP = 72;        // LDS row stride (64 + 8 pad)

DEVI unsigned short f2b(float f) {
  union { float f; unsigned u; } v; v.f = f;
  unsigned r = v.u + 0x7FFFu + ((v.u >> 16) & 1u);
  return (unsigned short)(r >> 16);
}
DEVI float b2f(unsigned short h) {
  union { unsigned u; float f; } v; v.u = ((unsigned)h) << 16; return v.f;
}

// ---------------- prep kernels ----------------

__global__ __launch_bounds__(256) void k_cvt(const float* __restrict__ x,
                                             unsigned short* __restrict__ o, int n) {
  int i = (blockIdx.x * 256 + threadIdx.x) * 8;
  if (i >= n) return;
  float4 a = *(const float4*)(x + i), b = *(const float4*)(x + i + 4);
  uint4 u;
  u.x = (unsigned)f2b(a.x) | ((unsigned)f2b(a.y) << 16);
  u.y = (unsigned)f2b(a.z) | ((unsigned)f2b(a.w) << 16);
  u.z = (unsigned)f2b(b.x) | ((unsigned)f2b(b.y) << 16);
  u.w = (unsigned)f2b(b.z) | ((unsigned)f2b(b.w) << 16);
  *(uint4*)(o + i) = u;
}

__global__ __launch_bounds__(256) void k_cvt_wa(const float* __restrict__ Wih,
                                                unsigned short* __restrict__ Wa) {
  int u = blockIdx.x * 256 + threadIdx.x;
  int g = u >> 6, d = (u & 63) * 8;
  const float* p = Wih + (size_t)g * DC + d;
  float4 a = *(const float4*)p, b = *(const float4*)(p + 4);
  uint4 o;
  o.x = (unsigned)f2b(a.x) | ((unsigned)f2b(a.y) << 16);
  o.y = (unsigned)f2b(a.z) | ((unsigned)f2b(a.w) << 16);
  o.z = (unsigned)f2b(b.x) | ((unsigned)f2b(b.y) << 16);
  o.w = (unsigned)f2b(b.z) | ((unsigned)f2b(b.w) << 16);
  *(uint4*)(Wa + (size_t)g * Dd + d) = o;
}

__global__ __launch_bounds__(256) void k_cvt_wct(const float* __restrict__ Wih,
                                                 unsigned short* __restrict__ WcT) {
  int g = blockIdx.x * 256 + threadIdx.x;
  int c = blockIdx.y;
  WcT[(size_t)c * G3 + g] = f2b(Wih[(size_t)g * DC + Dd + c]);
}

__global__ __launch_bounds__(256) void k_pid(const float* __restrict__ ts,
                                             int* __restrict__ pid) {
  int bt = blockIdx.x * 256 + threadIdx.x;
  int t = bt & (Tt - 1);
  if (t == 0) { pid[bt] = -1; return; }
  const float* p = ts + (size_t)(bt - 1) * Cc;
  int id = 0;
  for (int c = 0; c < Cc; c += 4) {
    float4 v = *(const float4*)(p + c);
    if (v.x > 0.5f) id = c;
    if (v.y > 0.5f) id = c + 1;
    if (v.z > 0.5f) id = c + 2;
    if (v.w > 0.5f) id = c + 3;
  }
  pid[bt] = id;
}

// ---------------- gates tile: reg-staged LDS, BK=64 ----------------
// sA/sB: [128][LDP] bf16 (36.9KB total). Identical K order to round-11 =>
// bit-identical acc.
DEVI void gates_tile(int mi, int ni, const unsigned short* __restrict__ Xb,
                     const unsigned short* __restrict__ Wa,
                     const unsigned short* __restrict__ WcT,
                     const float* __restrict__ bih,
                     const int* __restrict__ pid,
                     unsigned short* __restrict__ gx, int t0c,
                     unsigned short* sA, unsigned short* sB) {
  const int m0 = mi * 128, n0 = ni * 128;
  const int tid = threadIdx.x;
  const int l = tid & 63, w = tid >> 6;
  const int wm = w >> 1, wn = w & 1;
  const int r0l = 64 * wm, c0l = 64 * wn;       // LDS-local quadrant
  const int lr = l & 15, lk = (l >> 4) * 8;

  // staging map: 4 chunks/thread; chunk ch -> row=ch>>3, q=ch&7 (8 elems)
  int srow[4], sq[4];
  size_t gA[4], gB[4];
#pragma unroll
  for (int c = 0; c < 4; ++c) {
    int ch = tid + c * 256;
    srow[c] = ch >> 3; sq[c] = ch & 7;
    int mrow = m0 + srow[c];
    gA[c] = ((size_t)((mrow >> 5) * Tt + t0c + (mrow & 31))) * Dd + sq[c] * 8;
    gB[c] = (size_t)(n0 + srow[c]) * Dd + sq[c] * 8;
  }

  f32x4 acc[4][4] = {};
  for (int ks = 0; ks < 8; ++ks) {
    int k0 = ks * 64;
    __syncthreads();  // protect LDS from previous iteration's readers
#pragma unroll
    for (int c = 0; c < 4; ++c) {
      bf16x8 av = *(const bf16x8*)(Xb + gA[c] + k0);
      bf16x8 bv = *(const bf16x8*)(Wa + gB[c] + k0);
      *(bf16x8*)(sA + srow[c] * LDP + sq[c] * 8) = av;
      *(bf16x8*)(sB + srow[c] * LDP + sq[c] * 8) = bv;
    }
    __syncthreads();
#pragma unroll
    for (int kk = 0; kk < 2; ++kk) {
      int kc = kk * 32 + lk;
      bf16x8 a[4], b[4];
#pragma unroll
      for (int mf = 0; mf < 4; ++mf)
        a[mf] = *(const bf16x8*)(sA + (r0l + 16 * mf + lr) * LDP + kc);
#pragma unroll
      for (int nf = 0; nf < 4; ++nf)
        b[nf] = *(const bf16x8*)(sB + (c0l + 16 * nf + lr) * LDP + kc);
#pragma unroll
      for (int mf = 0; mf < 4; ++mf)
#pragma unroll
        for (int nf = 0; nf < 4; ++nf)
          acc[mf][nf] = __builtin_amdgcn_mfma_f32_16x16x32_bf16(a[mf], b[nf], acc[mf][nf], 0, 0, 0);
    }
  }

  const int ri = (l >> 4) * 4;
  const int r0 = m0 + 64 * wm, c0 = n0 + 64 * wn;
  for (int mf = 0; mf < 4; ++mf) {
    int rowb = r0 + 16 * mf + ri;
    int pd[4];
#pragma unroll
    for (int i = 0; i < 4; ++i) {
      int rr = rowb + i;
      pd[i] = pid[(size_t)(rr >> 5) * Tt + t0c + (rr & 31)];
    }
    for (int nf = 0; nf < 4; ++nf) {
      int g = c0 + 16 * nf + lr;
      float bi = bih[g];
#pragma unroll
      for (int i = 0; i < 4; ++i) {
        float v = acc[mf][nf][i] + bi;
        if (pd[i] >= 0) v += b2f(WcT[(size_t)pd[i] * G3 + g]);
        gx[(size_t)(rowb + i) * G3 + g] = f2b(v);
      }
    }
  }
}

__global__ __launch_bounds__(256) void k_gates(const unsigned short* __restrict__ Xb,
                                               const unsigned short* __restrict__ Wa,
                                               const unsigned short* __restrict__ WcT,
                                               const float* __restrict__ bih,
                                               const int* __restrict__ pid,
                                               unsigned short* __restrict__ gx, int t0c) {
  __shared__ unsigned short sA[128 * LDP], sB[128 * LDP];
  gates_tile(blockIdx.x, blockIdx.y, Xb, Wa, WcT, bih, pid, gx, t0c, sA, sB);
}

// ---------------- logits tile ----------------
DEVI void logits_tile(int blk, const unsigned short* __restrict__ hsc,
                      const unsigned short* __restrict__ Wo,
                      const float* __restrict__ bout,
                      float* __restrict__ out, int t0) {
  int l = threadIdx.x & 63, w = threadIdx.x >> 6;
  int lr = l & 15, lk = (l >> 4) * 8;
  int r0 = blk * 64 + 16 * w;
  f32x4 acc[8] = {};
  for (int kk = 0; kk < 32; ++kk) {
    int k = kk * 32 + lk;
    bf16x8 a = *(const bf16x8*)(hsc + (size_t)(r0 + lr) * Hh + k);
#pragma unroll
    for (int nf = 0; nf < 8; ++nf) {
      bf16x8 b = *(const bf16x8*)(Wo + (size_t)(16 * nf + lr) * Hh + k);
      acc[nf] = __builtin_amdgcn_mfma_f32_16x16x32_bf16(a, b, acc[nf], 0, 0, 0);
    }
  }
  int ri = (l >> 4) * 4;
  for (int nf = 0; nf < 8; ++nf) {
    int c = 16 * nf + lr;
    float bo = bout[c];
#pragma unroll
    for (int i = 0; i < 4; ++i) {
      int m = r0 + ri + i;
      int grow = (m >> 5) * Tt + t0 + (m & 31);
      out[(size_t)grow * Cc + c] = acc[nf][i] + bo;
    }
  }
}

// ---------------- combo: gates(c+1) + logits(c) ----------------
__global__ __launch_bounds__(256) void k_combo(
    const unsigned short* __restrict__ Xb, const unsigned short* __restrict__ Wa,
    const unsigned short* __restrict__ WcT, const float* __restrict__ bih,
    const int* __restrict__ pid, unsigned short* __restrict__ gxNext, int doGates,
    const unsigned short* __restrict__ hsc, const unsigned short* __restrict__ Wob,
    const float* __restrict__ bou, float* __restrict__ outp, int t0) {
  __shared__ unsigned short sA[128 * LDP], sB[128 * LDP];
  int bid = blockIdx.x;
  if (bid < 1536) {
    if (doGates)
      gates_tile(bid & 63, bid >> 6, Xb, Wa, WcT, bih, pid, gxNext, t0 + TC, sA, sB);
  } else {
    logits_tile(bid - 1536, hsc, Wob, bou, outp, t0);
  }
}

// ---------------- recurrent scan chunk (round-10/11 proven, unchanged) ----------------
__global__ __launch_bounds__(256, 1) void k_scan(const unsigned short* __restrict__ Whh,
                                                 const float* __restrict__ bhh,
                                                 const unsigned short* __restrict__ gx,
                                                 unsigned short* __restrict__ hring,
                                                 unsigned short* __restrict__ hsc,
                                                 unsigned int* __restrict__ notify,
                                                 int t0) {
  __shared__ float red[4 * 32 * 100];  // [wave][row32][3*32 pad100] = 51.2KB
  const int tid = threadIdx.x;
  const int l = tid & 63, w = tid >> 6;
  const int bid = blockIdx.x;
  const int mg = bid & 7, cb = bid >> 3;
  const int lr = l & 15, lk = (l >> 4) * 8;
  const int hcolBase = 32 * cb;
  const int ri = (l >> 4) * 4;

  bf16x8 Breg[6][8];
#pragma unroll
  for (int nf = 0; nf < 6; ++nf) {
    int wrow = (nf >> 1) * Hh + hcolBase + (nf & 1) * 16 + lr;
#pragma unroll
    for (int kk = 0; kk < 8; ++kk) {
      int k = 256 * w + 32 * kk + lk;
      Breg[nf][kk] = *(const bf16x8*)(Whh + (size_t)wrow * Hh + k);
    }
  }

  const int erow = tid >> 3, ej0 = (tid & 7) * 4;
  const int eb = 32 * mg + erow;
  const int ecol = hcolBase + ej0;
  const float4 bhr4 = *(const float4*)(bhh + ecol);
  const float4 bhz4 = *(const float4*)(bhh + Hh + ecol);
  const float4 bhn4 = *(const float4*)(bhh + 2 * Hh + ecol);

  u64 hsave = 0;

  for (int tl = 0; tl < TC; ++tl) {
    const int t = t0 + tl;
    const unsigned short* hcur = hring + (size_t)(t % SLOTS) * (Bb * Hh);
    u64* hnq = (u64*)hring + (size_t)((t + 1) % SLOTS) * (Bb * Hh / 4);

    const size_t gxo = (size_t)(eb * TC + tl) * G3;
    uint2 gr = *(const uint2*)(gx + gxo + ecol);
    uint2 gz = *(const uint2*)(gx + gxo + Hh + ecol);
    uint2 gn = *(const uint2*)(gx + gxo + 2 * Hh + ecol);

    if (t > 0) {
      const unsigned int* np = notify + (mg << 6) + (l & 31);
      for (;;) {
        unsigned int v = __hip_atomic_load(np, __ATOMIC_RELAXED,
                                           __HIP_MEMORY_SCOPE_AGENT);
        if (__all((int)(v >= (unsigned)t))) break;
      }
    }
    asm volatile("" ::: "memory");

    u64 hprev = (tl == 0) ? *(const u64*)(hcur + (size_t)eb * Hh + ecol) : hsave;

    f32x4 acc[2][6] = {};
#pragma unroll
    for (int kk = 0; kk < 8; ++kk) {
      int k = 256 * w + 32 * kk + lk;
      bf16x8 a[2];
#pragma unroll
      for (int mf = 0; mf < 2; ++mf)
        a[mf] = *(const bf16x8*)(hcur + (size_t)(32 * mg + 16 * mf + lr) * Hh + k);
#pragma unroll
      for (int mf = 0; mf < 2; ++mf)
#pragma unroll
        for (int nf = 0; nf < 6; ++nf)
          acc[mf][nf] = __builtin_amdgcn_mfma_f32_16x16x32_bf16(a[mf], Breg[nf][kk], acc[mf][nf], 0, 0, 0);
    }

#pragma unroll
    for (int mf = 0; mf < 2; ++mf)
#pragma unroll
      for (int nf = 0; nf < 6; ++nf)
#pragma unroll
        for (int i = 0; i < 4; ++i)
          red[(w * 32 + 16 * mf + ri + i) * 100 + (nf >> 1) * 32 + (nf & 1) * 16 + lr] = acc[mf][nf][i];
    __syncthreads();

    f32x4 vr = {}, vz = {}, vn = {};
#pragma unroll
    for (int w2 = 0; w2 < 4; ++w2) {
      const float* rp = &red[(w2 * 32 + erow) * 100];
      vr += *(const f32x4*)(rp + ej0);
      vz += *(const f32x4*)(rp + 32 + ej0);
      vn += *(const f32x4*)(rp + 64 + ej0);
    }
    unsigned short grs[4] = {(unsigned short)gr.x, (unsigned short)(gr.x >> 16),
                             (unsigned short)gr.y, (unsigned short)(gr.y >> 16)};
    unsigned short gzs[4] = {(unsigned short)gz.x, (unsigned short)(gz.x >> 16),
                             (unsigned short)gz.y, (unsigned short)(gz.y >> 16)};
    unsigned short gns[4] = {(unsigned short)gn.x, (unsigned short)(gn.x >> 16),
                             (unsigned short)gn.y, (unsigned short)(gn.y >> 16)};
    u64 ho = 0;
#pragma unroll
    for (int i = 0; i < 4; ++i) {
      float hr = vr[i] + (&bhr4.x)[i];
      float hz = vz[i] + (&bhz4.x)[i];
      float hn = vn[i] + (&bhn4.x)[i];
      float xr = b2f(grs[i]), xz = b2f(gzs[i]), xn = b2f(gns[i]);
      float rg = 1.f / (1.f + __expf(-(xr + hr)));
      float zg = 1.f / (1.f + __expf(-(xz + hz)));
      float pre = xn + rg * hn;
      pre = fminf(fmaxf(pre, -15.f), 15.f);
      float e = __expf(-2.f * pre);
      float ng = (1.f - e) / (1.f + e);
      float hp = b2f((unsigned short)(hprev >> (16 * i)));
      float hv = (1.f - zg) * ng + zg * hp;
      ho |= (u64)f2b(hv) << (16 * i);
    }
    __hip_atomic_store(hnq + ((size_t)eb * Hh + ecol) / 4, ho,
                       __ATOMIC_RELAXED, __HIP_MEMORY_SCOPE_AGENT);
    hsave = ho;

    asm volatile("s_waitcnt vmcnt(0)" ::: "memory");  // h stores acked at MALL
    __syncthreads();
    if (tid == 0)
      __hip_atomic_store(notify + (mg << 6) + cb, (unsigned)(t + 1),
                         __ATOMIC_RELAXED, __HIP_MEMORY_SCOPE_AGENT);
    *(u64*)(hsc + (size_t)(eb * TC + tl) * Hh + ecol) = ho;
  }
}

// ---------------- launch ----------------
extern "C" void kernel_launch(void* const* d_in, const int* in_sizes, int n_in,
                              void* d_out, int out_size, void* d_ws, size_t ws_size,
                              hipStream_t stream) {
  const float* gru = (const float*)d_in[0];
  const float* ts  = (const float*)d_in[1];
  const float* Wih = (const float*)d_in[2];
  const float* bih = (const float*)d_in[3];
  const float* Whh = (const float*)d_in[4];
  const float* bhh = (const float*)d_in[5];
  const float* Wou = (const float*)d_in[6];
  const float* bou = (const float*)d_in[7];
  float* out = (float*)d_out;

  char* ws = (char*)d_ws;
  size_t off = 0;
  auto alloc = [&](size_t bytes) -> void* {
    void* p = ws + off;
    off += (bytes + 255) & ~(size_t)255;
    return p;
  };
  unsigned short* Wa    = (unsigned short*)alloc((size_t)G3 * Dd * 2);        // 3.1MB
  unsigned short* WcT   = (unsigned short*)alloc((size_t)Cc * G3 * 2);        // 0.8MB
  unsigned short* Whb   = (unsigned short*)alloc((size_t)G3 * Hh * 2);        // 6.3MB
  unsigned short* Wob   = (unsigned short*)alloc((size_t)Cc * Hh * 2);        // 0.26MB
  int*            pid   = (int*)alloc((size_t)Bb * Tt * 4);                   // 0.26MB
  unsigned short* hring = (unsigned short*)alloc((size_t)SLOTS * Bb * Hh * 2);// 17.3MB
  unsigned int*   nfy   = (unsigned int*)alloc((size_t)8 * 64 * 4);
  unsigned short* Xb    = (unsigned short*)alloc((size_t)Bb * Tt * Dd * 2);   // 67.1MB
  unsigned short* gx    = (unsigned short*)alloc((size_t)Bb * TC * G3 * 2);   // 50.3MB
  unsigned short* hsc   = (unsigned short*)alloc((size_t)Bb * TC * Hh * 2);   // 16.8MB
  if (ws_size < off) return;  // ~155MiB; round-9 proved >=163MiB exists

  int nX = Bb * Tt * Dd;
  k_cvt<<<nX / 2048, 256, 0, stream>>>(gru, Xb, nX);
  k_cvt<<<(G3 * Hh) / 2048, 256, 0, stream>>>(Whh, Whb, G3 * Hh);
  k_cvt<<<(Cc * Hh) / 2048, 256, 0, stream>>>(Wou, Wob, Cc * Hh);
  k_cvt_wa<<<(G3 * 64) / 256, 256, 0, stream>>>(Wih, Wa);
  k_cvt_wct<<<dim3(G3 / 256, Cc), 256, 0, stream>>>(Wih, WcT);
  k_pid<<<(Bb * Tt) / 256, 256, 0, stream>>>(ts, pid);
  hipMemsetAsync(hring, 0, (size_t)Bb * Hh * 2, stream);  // slot 0 = h(0) = 0
  hipMemsetAsync(nfy, 0, (size_t)8 * 64 * 4, stream);

  // prologue: gates for chunk 0
  k_gates<<<dim3(64, 24), 256, 0, stream>>>(Xb, Wa, WcT, bih, pid, gx, 0);

  for (int c = 0; c < NC; ++c) {
    int t0 = c * TC;
    k_scan<<<dim3(256), dim3(256), 0, stream>>>(Whb, bhh, gx, hring, hsc, nfy, t0);
    k_combo<<<dim3(1664), dim3(256), 0, stream>>>(
        Xb, Wa, WcT, bih, pid, gx, (c + 1 < NC) ? 1 : 0,
        hsc, Wob, bou, out, t0);
  }
}

// Round 14
// 2319.029 us; speedup vs baseline: 1.4870x; 1.0146x over previous
//
#include <hip/hip_runtime.h>

// TerminalGRU: B=256 T=256 D=512 H=1024 C=128
// Round-14 (from R13 @2.35ms): two surgical scan-wait cuts, arithmetic untouched:
//  a) per-wave producer polling: wave w's MFMA needs K [256w,+256) = producers
//     8w..8w+7 only -> poll those 8 words, start MFMA early (skew overlap).
//  b) hsc eliminated: logits reads h straight from the 33-slot ring (slot =
//     (t0+tl+1)%33; combo(c) runs before scan(c+1) overwrites). Scan loses its
//     per-step 0.5MB history store (WRITE_SIZE halves).
// Pipeline: prep+cvtX -> gates(0) -> loop{ scan(c); combo: gates(c+1)+logits(c) }

#define DEVI __device__ __forceinline__

typedef __bf16 bf16x8 __attribute__((ext_vector_type(8)));
typedef float f32x4 __attribute__((ext_vector_type(4)));
typedef unsigned long long u64;

static constexpr int Bb = 256, Tt = 256, Dd = 512, Hh = 1024, Cc = 128;
static constexpr int G3 = 3072, DC = 640, TC = 32, NC = Tt / TC;
static constexpr int SLOTS = TC + 1;  // 33-slot h ring
static constexpr int LDP = 72;        // LDS row stride (64 + 8 pad)

DEVI unsigned short f2b(float f) {
  union { float f; unsigned u; } v; v.f = f;
  unsigned r = v.u + 0x7FFFu + ((v.u >> 16) & 1u);
  return (unsigned short)(r >> 16);
}
DEVI float b2f(unsigned short h) {
  union { unsigned u; float f; } v; v.u = ((unsigned)h) << 16; return v.f;
}

// ---------------- prep kernels ----------------

__global__ __launch_bounds__(256) void k_cvt(const float* __restrict__ x,
                                             unsigned short* __restrict__ o, int n) {
  int i = (blockIdx.x * 256 + threadIdx.x) * 8;
  if (i >= n) return;
  float4 a = *(const float4*)(x + i), b = *(const float4*)(x + i + 4);
  uint4 u;
  u.x = (unsigned)f2b(a.x) | ((unsigned)f2b(a.y) << 16);
  u.y = (unsigned)f2b(a.z) | ((unsigned)f2b(a.w) << 16);
  u.z = (unsigned)f2b(b.x) | ((unsigned)f2b(b.y) << 16);
  u.w = (unsigned)f2b(b.z) | ((unsigned)f2b(b.w) << 16);
  *(uint4*)(o + i) = u;
}

__global__ __launch_bounds__(256) void k_cvt_wa(const float* __restrict__ Wih,
                                                unsigned short* __restrict__ Wa) {
  int u = blockIdx.x * 256 + threadIdx.x;
  int g = u >> 6, d = (u & 63) * 8;
  const float* p = Wih + (size_t)g * DC + d;
  float4 a = *(const float4*)p, b = *(const float4*)(p + 4);
  uint4 o;
  o.x = (unsigned)f2b(a.x) | ((unsigned)f2b(a.y) << 16);
  o.y = (unsigned)f2b(a.z) | ((unsigned)f2b(a.w) << 16);
  o.z = (unsigned)f2b(b.x) | ((unsigned)f2b(b.y) << 16);
  o.w = (unsigned)f2b(b.z) | ((unsigned)f2b(b.w) << 16);
  *(uint4*)(Wa + (size_t)g * Dd + d) = o;
}

__global__ __launch_bounds__(256) void k_cvt_wct(const float* __restrict__ Wih,
                                                 unsigned short* __restrict__ WcT) {
  int g = blockIdx.x * 256 + threadIdx.x;
  int c = blockIdx.y;
  WcT[(size_t)c * G3 + g] = f2b(Wih[(size_t)g * DC + Dd + c]);
}

__global__ __launch_bounds__(256) void k_pid(const float* __restrict__ ts,
                                             int* __restrict__ pid) {
  int bt = blockIdx.x * 256 + threadIdx.x;
  int t = bt & (Tt - 1);
  if (t == 0) { pid[bt] = -1; return; }
  const float* p = ts + (size_t)(bt - 1) * Cc;
  int id = 0;
  for (int c = 0; c < Cc; c += 4) {
    float4 v = *(const float4*)(p + c);
    if (v.x > 0.5f) id = c;
    if (v.y > 0.5f) id = c + 1;
    if (v.z > 0.5f) id = c + 2;
    if (v.w > 0.5f) id = c + 3;
  }
  pid[bt] = id;
}

// ---------------- gates tile: reg-staged LDS, BK=64 (R13 proven) ----------------
DEVI void gates_tile(int mi, int ni, const unsigned short* __restrict__ Xb,
                     const unsigned short* __restrict__ Wa,
                     const unsigned short* __restrict__ WcT,
                     const float* __restrict__ bih,
                     const int* __restrict__ pid,
                     unsigned short* __restrict__ gx, int t0c,
                     unsigned short* sA, unsigned short* sB) {
  const int m0 = mi * 128, n0 = ni * 128;
  const int tid = threadIdx.x;
  const int l = tid & 63, w = tid >> 6;
  const int wm = w >> 1, wn = w & 1;
  const int r0l = 64 * wm, c0l = 64 * wn;
  const int lr = l & 15, lk = (l >> 4) * 8;

  int srow[4], sq[4];
  size_t gA[4], gB[4];
#pragma unroll
  for (int c = 0; c < 4; ++c) {
    int ch = tid + c * 256;
    srow[c] = ch >> 3; sq[c] = ch & 7;
    int mrow = m0 + srow[c];
    gA[c] = ((size_t)((mrow >> 5) * Tt + t0c + (mrow & 31))) * Dd + sq[c] * 8;
    gB[c] = (size_t)(n0 + srow[c]) * Dd + sq[c] * 8;
  }

  f32x4 acc[4][4] = {};
  for (int ks = 0; ks < 8; ++ks) {
    int k0 = ks * 64;
    __syncthreads();
#pragma unroll
    for (int c = 0; c < 4; ++c) {
      bf16x8 av = *(const bf16x8*)(Xb + gA[c] + k0);
      bf16x8 bv = *(const bf16x8*)(Wa + gB[c] + k0);
      *(bf16x8*)(sA + srow[c] * LDP + sq[c] * 8) = av;
      *(bf16x8*)(sB + srow[c] * LDP + sq[c] * 8) = bv;
    }
    __syncthreads();
#pragma unroll
    for (int kk = 0; kk < 2; ++kk) {
      int kc = kk * 32 + lk;
      bf16x8 a[4], b[4];
#pragma unroll
      for (int mf = 0; mf < 4; ++mf)
        a[mf] = *(const bf16x8*)(sA + (r0l + 16 * mf + lr) * LDP + kc);
#pragma unroll
      for (int nf = 0; nf < 4; ++nf)
        b[nf] = *(const bf16x8*)(sB + (c0l + 16 * nf + lr) * LDP + kc);
#pragma unroll
      for (int mf = 0; mf < 4; ++mf)
#pragma unroll
        for (int nf = 0; nf < 4; ++nf)
          acc[mf][nf] = __builtin_amdgcn_mfma_f32_16x16x32_bf16(a[mf], b[nf], acc[mf][nf], 0, 0, 0);
    }
  }

  const int ri = (l >> 4) * 4;
  const int r0 = m0 + 64 * wm, c0 = n0 + 64 * wn;
  for (int mf = 0; mf < 4; ++mf) {
    int rowb = r0 + 16 * mf + ri;
    int pd[4];
#pragma unroll
    for (int i = 0; i < 4; ++i) {
      int rr = rowb + i;
      pd[i] = pid[(size_t)(rr >> 5) * Tt + t0c + (rr & 31)];
    }
    for (int nf = 0; nf < 4; ++nf) {
      int g = c0 + 16 * nf + lr;
      float bi = bih[g];
#pragma unroll
      for (int i = 0; i < 4; ++i) {
        float v = acc[mf][nf][i] + bi;
        if (pd[i] >= 0) v += b2f(WcT[(size_t)pd[i] * G3 + g]);
        gx[(size_t)(rowb + i) * G3 + g] = f2b(v);
      }
    }
  }
}

__global__ __launch_bounds__(256) void k_gates(const unsigned short* __restrict__ Xb,
                                               const unsigned short* __restrict__ Wa,
                                               const unsigned short* __restrict__ WcT,
                                               const float* __restrict__ bih,
                                               const int* __restrict__ pid,
                                               unsigned short* __restrict__ gx, int t0c) {
  __shared__ unsigned short sA[128 * LDP], sB[128 * LDP];
  gates_tile(blockIdx.x, blockIdx.y, Xb, Wa, WcT, bih, pid, gx, t0c, sA, sB);
}

// ---------------- logits tile (reads h straight from the ring) ----------------
DEVI void logits_tile(int blk, const unsigned short* __restrict__ hring,
                      const unsigned short* __restrict__ Wo,
                      const float* __restrict__ bout,
                      float* __restrict__ out, int t0) {
  int l = threadIdx.x & 63, w = threadIdx.x >> 6;
  int lr = l & 15, lk = (l >> 4) * 8;
  int r0 = blk * 64 + 16 * w;
  // this lane's A row: chunk-local m = r0+lr -> (b, tl) -> ring slot t0+tl+1
  int am = r0 + lr;
  int ab = am >> 5, atl = am & 31;
  const unsigned short* arow =
      hring + (size_t)((t0 + atl + 1) % SLOTS) * (Bb * Hh) + (size_t)ab * Hh;
  f32x4 acc[8] = {};
  for (int kk = 0; kk < 32; ++kk) {
    int k = kk * 32 + lk;
    bf16x8 a = *(const bf16x8*)(arow + k);
#pragma unroll
    for (int nf = 0; nf < 8; ++nf) {
      bf16x8 b = *(const bf16x8*)(Wo + (size_t)(16 * nf + lr) * Hh + k);
      acc[nf] = __builtin_amdgcn_mfma_f32_16x16x32_bf16(a, b, acc[nf], 0, 0, 0);
    }
  }
  int ri = (l >> 4) * 4;
  for (int nf = 0; nf < 8; ++nf) {
    int c = 16 * nf + lr;
    float bo = bout[c];
#pragma unroll
    for (int i = 0; i < 4; ++i) {
      int m = r0 + ri + i;
      int grow = (m >> 5) * Tt + t0 + (m & 31);
      out[(size_t)grow * Cc + c] = acc[nf][i] + bo;
    }
  }
}

// ---------------- combo: gates(c+1) + logits(c) ----------------
__global__ __launch_bounds__(256) void k_combo(
    const unsigned short* __restrict__ Xb, const unsigned short* __restrict__ Wa,
    const unsigned short* __restrict__ WcT, const float* __restrict__ bih,
    const int* __restrict__ pid, unsigned short* __restrict__ gxNext, int doGates,
    const unsigned short* __restrict__ hring, const unsigned short* __restrict__ Wob,
    const float* __restrict__ bou, float* __restrict__ outp, int t0) {
  __shared__ unsigned short sA[128 * LDP], sB[128 * LDP];
  int bid = blockIdx.x;
  if (bid < 1536) {
    if (doGates)
      gates_tile(bid & 63, bid >> 6, Xb, Wa, WcT, bih, pid, gxNext, t0 + TC, sA, sB);
  } else {
    logits_tile(bid - 1536, hring, Wob, bou, outp, t0);
  }
}

// ---------------- recurrent scan chunk ----------------
// 256 blocks x 256 threads. mg = bid&7 (group, rows [32mg,+32)), cb = bid>>3
// (hcols [32cb,+32)). Wave w K-slice [256w,+256) -> producers 8w..8w+7 ONLY:
// per-wave poll of its own 8 notify words, MFMA starts as soon as they land.
__global__ __launch_bounds__(256, 1) void k_scan(const unsigned short* __restrict__ Whh,
                                                 const float* __restrict__ bhh,
                                                 const unsigned short* __restrict__ gx,
                                                 unsigned short* __restrict__ hring,
                                                 unsigned int* __restrict__ notify,
                                                 int t0) {
  __shared__ float red[4 * 32 * 100];  // [wave][row32][3*32 pad100] = 51.2KB
  const int tid = threadIdx.x;
  const int l = tid & 63, w = tid >> 6;
  const int bid = blockIdx.x;
  const int mg = bid & 7, cb = bid >> 3;
  const int lr = l & 15, lk = (l >> 4) * 8;
  const int hcolBase = 32 * cb;
  const int ri = (l >> 4) * 4;

  bf16x8 Breg[6][8];
#pragma unroll
  for (int nf = 0; nf < 6; ++nf) {
    int wrow = (nf >> 1) * Hh + hcolBase + (nf & 1) * 16 + lr;
#pragma unroll
    for (int kk = 0; kk < 8; ++kk) {
      int k = 256 * w + 32 * kk + lk;
      Breg[nf][kk] = *(const bf16x8*)(Whh + (size_t)wrow * Hh + k);
    }
  }

  const int erow = tid >> 3, ej0 = (tid & 7) * 4;
  const int eb = 32 * mg + erow;
  const int ecol = hcolBase + ej0;
  const float4 bhr4 = *(const float4*)(bhh + ecol);
  const float4 bhz4 = *(const float4*)(bhh + Hh + ecol);
  const float4 bhn4 = *(const float4*)(bhh + 2 * Hh + ecol);

  u64 hsave = 0;

  for (int tl = 0; tl < TC; ++tl) {
    const int t = t0 + tl;
    const unsigned short* hcur = hring + (size_t)(t % SLOTS) * (Bb * Hh);
    u64* hnq = (u64*)hring + (size_t)((t + 1) % SLOTS) * (Bb * Hh / 4);

    const size_t gxo = (size_t)(eb * TC + tl) * G3;
    uint2 gr = *(const uint2*)(gx + gxo + ecol);
    uint2 gz = *(const uint2*)(gx + gxo + Hh + ecol);
    uint2 gn = *(const uint2*)(gx + gxo + 2 * Hh + ecol);

    // per-wave wait: only this wave's 8 K-slice producers
    if (t > 0) {
      const unsigned int* np = notify + (mg << 6) + 8 * w + (l & 7);
      for (;;) {
        unsigned int v = __hip_atomic_load(np, __ATOMIC_RELAXED,
                                           __HIP_MEMORY_SCOPE_AGENT);
        if (__all((int)(v >= (unsigned)t))) break;
      }
    }
    asm volatile("" ::: "memory");

    u64 hprev = (tl == 0) ? *(const u64*)(hcur + (size_t)eb * Hh + ecol) : hsave;

    f32x4 acc[2][6] = {};
#pragma unroll
    for (int kk = 0; kk < 8; ++kk) {
      int k = 256 * w + 32 * kk + lk;
      bf16x8 a[2];
#pragma unroll
      for (int mf = 0; mf < 2; ++mf)
        a[mf] = *(const bf16x8*)(hcur + (size_t)(32 * mg + 16 * mf + lr) * Hh + k);
#pragma unroll
      for (int mf = 0; mf < 2; ++mf)
#pragma unroll
        for (int nf = 0; nf < 6; ++nf)
          acc[mf][nf] = __builtin_amdgcn_mfma_f32_16x16x32_bf16(a[mf], Breg[nf][kk], acc[mf][nf], 0, 0, 0);
    }

#pragma unroll
    for (int mf = 0; mf < 2; ++mf)
#pragma unroll
      for (int nf = 0; nf < 6; ++nf)
#pragma unroll
        for (int i = 0; i < 4; ++i)
          red[(w * 32 + 16 * mf + ri + i) * 100 + (nf >> 1) * 32 + (nf & 1) * 16 + lr] = acc[mf][nf][i];
    __syncthreads();

    f32x4 vr = {}, vz = {}, vn = {};
#pragma unroll
    for (int w2 = 0; w2 < 4; ++w2) {
      const float* rp = &red[(w2 * 32 + erow) * 100];
      vr += *(const f32x4*)(rp + ej0);
      vz += *(const f32x4*)(rp + 32 + ej0);
      vn += *(const f32x4*)(rp + 64 + ej0);
    }
    unsigned short grs[4] = {(unsigned short)gr.x, (unsigned short)(gr.x >> 16),
                             (unsigned short)gr.y, (unsigned short)(gr.y >> 16)};
    unsigned short gzs[4] = {(unsigned short)gz.x, (unsigned short)(gz.x >> 16),
                             (unsigned short)gz.y, (unsigned short)(gz.y >> 16)};
    unsigned short gns[4] = {(unsigned short)gn.x, (unsigned short)(gn.x >> 16),
                             (unsigned short)gn.y, (unsigned short)(gn.y >> 16)};
    u64 ho = 0;
#pragma unroll
    for (int i = 0; i < 4; ++i) {
      float hr = vr[i] + (&bhr4.x)[i];
      float hz = vz[i] + (&bhz4.x)[i];
      float hn = vn[i] + (&bhn4.x)[i];
      float xr = b2f(grs[i]), xz = b2f(gzs[i]), xn = b2f(gns[i]);
      float rg = 1.f / (1.f + __expf(-(xr + hr)));
      float zg = 1.f / (1.f + __expf(-(xz + hz)));
      float pre = xn + rg * hn;
      pre = fminf(fmaxf(pre, -15.f), 15.f);
      float e = __expf(-2.f * pre);
      float ng = (1.f - e) / (1.f + e);
      float hp = b2f((unsigned short)(hprev >> (16 * i)));
      float hv = (1.f - zg) * ng + zg * hp;
      ho |= (u64)f2b(hv) << (16 * i);
    }
    __hip_atomic_store(hnq + ((size_t)eb * Hh + ecol) / 4, ho,
                       __ATOMIC_RELAXED, __HIP_MEMORY_SCOPE_AGENT);
    hsave = ho;

    asm volatile("s_waitcnt vmcnt(0)" ::: "memory");  // h stores acked at MALL
    __syncthreads();  // all waves drained; also protects red[] reuse
    if (tid == 0)
      __hip_atomic_store(notify + (mg << 6) + cb, (unsigned)(t + 1),
                         __ATOMIC_RELAXED, __HIP_MEMORY_SCOPE_AGENT);
  }
}

// ---------------- launch ----------------
extern "C" void kernel_launch(void* const* d_in, const int* in_sizes, int n_in,
                              void* d_out, int out_size, void* d_ws, size_t ws_size,
                              hipStream_t stream) {
  const float* gru = (const float*)d_in[0];
  const float* ts  = (const float*)d_in[1];
  const float* Wih = (const float*)d_in[2];
  const float* bih = (const float*)d_in[3];
  const float* Whh = (const float*)d_in[4];
  const float* bhh = (const float*)d_in[5];
  const float* Wou = (const float*)d_in[6];
  const float* bou = (const float*)d_in[7];
  float* out = (float*)d_out;

  char* ws = (char*)d_ws;
  size_t off = 0;
  auto alloc = [&](size_t bytes) -> void* {
    void* p = ws + off;
    off += (bytes + 255) & ~(size_t)255;
    return p;
  };
  unsigned short* Wa    = (unsigned short*)alloc((size_t)G3 * Dd * 2);        // 3.1MB
  unsigned short* WcT   = (unsigned short*)alloc((size_t)Cc * G3 * 2);        // 0.8MB
  unsigned short* Whb   = (unsigned short*)alloc((size_t)G3 * Hh * 2);        // 6.3MB
  unsigned short* Wob   = (unsigned short*)alloc((size_t)Cc * Hh * 2);        // 0.26MB
  int*            pid   = (int*)alloc((size_t)Bb * Tt * 4);                   // 0.26MB
  unsigned short* hring = (unsigned short*)alloc((size_t)SLOTS * Bb * Hh * 2);// 17.3MB
  unsigned int*   nfy   = (unsigned int*)alloc((size_t)8 * 64 * 4);
  unsigned short* Xb    = (unsigned short*)alloc((size_t)Bb * Tt * Dd * 2);   // 67.1MB
  unsigned short* gx    = (unsigned short*)alloc((size_t)Bb * TC * G3 * 2);   // 50.3MB
  if (ws_size < off) return;  // ~138MiB; round-9 proved >=163MiB exists

  int nX = Bb * Tt * Dd;
  k_cvt<<<nX / 2048, 256, 0, stream>>>(gru, Xb, nX);
  k_cvt<<<(G3 * Hh) / 2048, 256, 0, stream>>>(Whh, Whb, G3 * Hh);
  k_cvt<<<(Cc * Hh) / 2048, 256, 0, stream>>>(Wou, Wob, Cc * Hh);
  k_cvt_wa<<<(G3 * 64) / 256, 256, 0, stream>>>(Wih, Wa);
  k_cvt_wct<<<dim3(G3 / 256, Cc), 256, 0, stream>>>(Wih, WcT);
  k_pid<<<(Bb * Tt) / 256, 256, 0, stream>>>(ts, pid);
  hipMemsetAsync(hring, 0, (size_t)Bb * Hh * 2, stream);  // slot 0 = h(0) = 0
  hipMemsetAsync(nfy, 0, (size_t)8 * 64 * 4, stream);

  // prologue: gates for chunk 0
  k_gates<<<dim3(64, 24), 256, 0, stream>>>(Xb, Wa, WcT, bih, pid, gx, 0);

  for (int c = 0; c < NC; ++c) {
    int t0 = c * TC;
    k_scan<<<dim3(256), dim3(256), 0, stream>>>(Whb, bhh, gx, hring, nfy, t0);
    k_combo<<<dim3(1664), dim3(256), 0, stream>>>(
        Xb, Wa, WcT, bih, pid, gx, (c + 1 < NC) ? 1 : 0,
        hring, Wob, bou, out, t0);
  }
}